// Round 20
// baseline (6795.765 us; speedup 1.0000x reference)
//
#include <hip/hip_runtime.h>
#include <cstdint>
#include <cstddef>

#define BB 32
#define SS 512
#define HH 512
#define JPB 16      // j columns per block
#define WR 64       // W rows per block (4 gates * JPB)
#define WST 520     // LDS row stride (bf16 elems; 1040B)

typedef short v8s __attribute__((ext_vector_type(8)));
typedef float v4f __attribute__((ext_vector_type(4)));
typedef unsigned int v4u __attribute__((ext_vector_type(4)));
typedef unsigned long long u64t;

static __device__ __forceinline__ float b2f(unsigned short u) {
    union { unsigned int i; float f; } v; v.i = ((unsigned int)u) << 16; return v.f;
}
static __device__ __forceinline__ unsigned short f2b(float f) {
    union { float f; unsigned int i; } v; v.f = f;
    unsigned int u = v.i;
    return (unsigned short)((u + 0x7fffu + ((u >> 16) & 1u)) >> 16);  // RNE
}
static __device__ __forceinline__ void split1(float f, short& hi, short& lo) {
    const unsigned short h = f2b(f);
    hi = (short)h;
    lo = (short)f2b(f - b2f(h));
}

#define MFMA(a, b, c) __builtin_amdgcn_mfma_f32_16x16x32_bf16((a), (b), (c), 0, 0, 0)

// Pre-split L1 Wih SECOND K-half (512..1023) to bf16-hi, rows reordered to
// fragment order: row' = jb*64 + r -> W row (r&3)*512 + jb*16 + (r>>2).
__global__ void wih1_presplit(const float* __restrict__ Wf,
                              const float* __restrict__ Wb,
                              unsigned short* __restrict__ whi)
{
    const size_t n = (size_t)2 * 2048 * 512;
    for (size_t i = (size_t)blockIdx.x * blockDim.x + threadIdx.x; i < n;
         i += (size_t)gridDim.x * blockDim.x) {
        const int dir = (int)(i >> 20);               // / (2048*512)
        const size_t rem = i & ((1u << 20) - 1);
        const int rp = (int)(rem >> 9);               // row' 0..2047
        const int kk = (int)(rem & 511);
        const int jb = rp >> 6;
        const int r  = rp & 63;
        const int R  = (r & 3) * HH + jb * JPB + (r >> 2);
        whi[i] = f2b((dir ? Wb : Wf)[(size_t)R * 1024 + 512 + kk]);
    }
}

// One bidirectional layer; persistent blocks; per-timestep producer flags.
// r20: BATCH-GROUP partition G=2 x J=32 (batch samples are independent ->
// exchange all-to-all is per (dir,group): 32 producers, h slice 16KB).
// Exchange bytes/step: 4MB -> 2MB (the confirmed r12 lever, structurally).
// Block = [16 batches]x[16 j](64 gate-cols); 4 waves = 4 N-tiles, M=16 frag.
// L0: Whh+Wih fully in LDS. L1: Wih K-half LDS, K-half streamed (presplit
// bf16, L2-hot, hidden under the wait per r17). Sync/publish = r16 style.
template<int DIN, bool L0>
__global__ __launch_bounds__(256, 1)
void lstm_layer(const void*  __restrict__ xin_,
                const float* __restrict__ Wih_f,   // [4H, DIN] f32
                const float* __restrict__ Whh_f,   // [4H, H]  f32
                const float* __restrict__ b_f,     // [4H]     f32
                const float* __restrict__ Wih_b,
                const float* __restrict__ Whh_b,
                const float* __restrict__ b_b,
                const unsigned short* __restrict__ wsp,  // L1: presplit Wih K-hi half
                void*  __restrict__ yout_,          // L0: bf16 [B,S,2H]; L1: f32 [B,S,2H]
                u64t*  __restrict__ hrec,           // [2dir][2grp][2par][16][128] u64
                unsigned int* __restrict__ flags,   // [2dir][2grp][S][64], zeroed
                float* __restrict__ hn,             // [2][B][H] f32 (L1) or nullptr
                float* __restrict__ cn)             // [2][B][H] f32 (L1) or nullptr
{
    constexpr int NKX = DIN / 32;

    extern __shared__ char smem[];
    unsigned short* WhhHi = (unsigned short*)smem;          // [64][WST]
    unsigned short* WihHi = WhhHi + WR * WST;               // [64][WST] (K 0..511)
    unsigned short* hHi   = WihHi + WR * WST;               // [16][WST]

    const int tid   = threadIdx.x;
    const int dir   = blockIdx.x >> 6;
    const int grp   = (blockIdx.x >> 5) & 1;
    const int jb    = blockIdx.x & 31;
    const int jbase = jb * JPB;

    const float* Wih = dir ? Wih_b : Wih_f;
    const float* Whh = dir ? Whh_b : Whh_f;
    const float* bv  = dir ? b_b  : b_f;

    // ---- stage Whh-hi + Wih-hi(K 0..511) into LDS; LDS row r -> W row
    //      R = (r&3)*HH + jbase + (r>>2) ----
    {
        const int r  = tid >> 2;              // 0..63
        const int c0 = (tid & 3) * 128;       // 0..384
        const int R  = (r & 3) * HH + jbase + (r >> 2);
        {
            const float* src = Whh + (size_t)R * HH + c0;
            #pragma unroll
            for (int c = 0; c < 128; c += 8) {
                v8s hi;
                #pragma unroll
                for (int e = 0; e < 8; ++e) hi[e] = (short)f2b(src[c + e]);
                *(v8s*)(WhhHi + r * WST + c0 + c) = hi;
            }
        }
        {
            const float* src = Wih + (size_t)R * DIN + c0;
            #pragma unroll
            for (int c = 0; c < 128; c += 8) {
                v8s hi;
                #pragma unroll
                for (int e = 0; e < 8; ++e) hi[e] = (short)f2b(src[c + e]);
                *(v8s*)(WihHi + r * WST + c0 + c) = hi;
            }
        }
    }

    const int lane = tid & 63;
    const int wv   = tid >> 6;       // wave = N-tile 0..3
    const int g    = lane >> 4;      // k-group
    const int rA   = lane & 15;

    const int col  = wv * 16 + rA;   // output gate-col 0..63 (= LDS B row)
    const int jl   = col >> 2;       // j within block 0..15
    const int p    = rA & 3;         // lane pos in gate subgroup

    const float bi_ = bv[0 * HH + jbase + jl];
    const float bf_ = bv[1 * HH + jbase + jl];
    const float bg_ = bv[2 * HH + jbase + jl];
    const float bo_ = bv[3 * HH + jbase + jl];

    __syncthreads();

    const int abatch = grp * 16 + rA;    // global batch of this lane's A-row
    const float*          aXf = L0 ? (const float*)xin_ + (size_t)abatch * SS * DIN + 8 * g : nullptr;
    const unsigned short* aXb = L0 ? nullptr : (const unsigned short*)xin_ + (size_t)abatch * SS * DIN + 8 * g;
    const unsigned short* bHh = WhhHi + col * WST + 8 * g;
    const unsigned short* bHx = WihHi + col * WST + 8 * g;
    const unsigned short* wspL = L0 ? nullptr
        : wsp + ((size_t)(dir * 2048 + jb * 64 + col)) * 512 + 8 * g;  // K 512..1023

    unsigned int* fbase = flags + (size_t)(dir * 2 + grp) * SS * 64;
    u64t* hrbase = hrec + (size_t)(dir * 2 + grp) * 2 * (16 * 128);

    const int batch  = 4 * g + p;        // local epilogue batch 0..15
    const int gbatch = grp * 16 + batch;
    const int c16 = tid & 63;            // stage: 16B unit (j 8*c16..8*c16+7)
    const int r0s = tid >> 6;            // stage: base row 0..3
    const int prod = c16 >> 1;           // producer jb' owning those j
    float creg = 0.f;

    for (int st = 0; st < SS; ++st) {
        const int t = dir ? (SS - 1 - st) : st;

        v4f acc0 = {0,0,0,0}, acc1 = {0,0,0,0};
        v4f acc4 = {0,0,0,0}, acc5 = {0,0,0,0};   // L0 a-lo terms

        // ---- x-part (pre-poll; overlapped with peers' publish) ----
        if (L0) {
            const float* aX = aXf + (size_t)t * DIN;
            #pragma unroll
            for (int kt = 0; kt < NKX; kt += 2) {
                v8s ah0, al0, ah1, al1;
                #pragma unroll
                for (int e = 0; e < 8; ++e) {
                    short h, l;
                    split1(aX[kt * 32 + e], h, l);       ah0[e] = h; al0[e] = l;
                    split1(aX[(kt + 1) * 32 + e], h, l); ah1[e] = h; al1[e] = l;
                }
                v8s wh0 = *(const v8s*)(bHx + kt * 32);
                v8s wh1 = *(const v8s*)(bHx + (kt + 1) * 32);
                acc0 = MFMA(ah0, wh0, acc0);
                acc1 = MFMA(ah1, wh1, acc1);
                acc4 = MFMA(al0, wh0, acc4);
                acc5 = MFMA(al1, wh1, acc5);
            }
        } else {
            const unsigned short* aX = aXb + (size_t)t * DIN;
            #pragma unroll
            for (int kt = 0; kt < 16; kt += 2) {          // K 0..511 from LDS
                v8s a0 = *(const v8s*)(aX + kt * 32);
                v8s a1 = *(const v8s*)(aX + (kt + 1) * 32);
                v8s wh0 = *(const v8s*)(bHx + kt * 32);
                v8s wh1 = *(const v8s*)(bHx + (kt + 1) * 32);
                acc0 = MFMA(a0, wh0, acc0);
                acc1 = MFMA(a1, wh1, acc1);
            }
            #pragma unroll
            for (int kt = 16; kt < 32; kt += 2) {         // K 512..1023 streamed
                v8s a0 = *(const v8s*)(aX + kt * 32);
                v8s a1 = *(const v8s*)(aX + (kt + 1) * 32);
                v8s wh0 = *(const v8s*)(wspL + (kt - 16) * 32);
                v8s wh1 = *(const v8s*)(wspL + (kt - 15) * 32);
                acc0 = MFMA(a0, wh0, acc0);
                acc1 = MFMA(a1, wh1, acc1);
            }
        }

        // ---- fused per-thread poll + 16B sc1 stage (group-local exchange) ----
        if (st > 0) {
            {
                const unsigned int* f = fbase + (size_t)(st - 1) * 64 + prod;
                int guard = 0;
                while (!__hip_atomic_load(f, __ATOMIC_RELAXED,
                                          __HIP_MEMORY_SCOPE_AGENT)) {
                    __builtin_amdgcn_s_sleep(1);
                    if (++guard > (1 << 26)) break;
                }
            }
            const char* hb = (const char*)(hrbase + ((st - 1) & 1) * (16 * 128))
                           + (size_t)r0s * 1024 + (size_t)c16 * 16;
            const char* p0 = hb;
            const char* p1 = hb + 1 * 4096;
            const char* p2 = hb + 2 * 4096;
            const char* p3 = hb + 3 * 4096;
            v4u v0, v1, v2, v3;
            asm volatile(
                "global_load_dwordx4 %[o0], %[a0], off sc1\n\t"
                "global_load_dwordx4 %[o1], %[a1], off sc1\n\t"
                "global_load_dwordx4 %[o2], %[a2], off sc1\n\t"
                "global_load_dwordx4 %[o3], %[a3], off sc1\n\t"
                "s_waitcnt vmcnt(0)"
                : [o0]"=&v"(v0), [o1]"=&v"(v1), [o2]"=&v"(v2), [o3]"=&v"(v3)
                : [a0]"v"(p0), [a1]"v"(p1), [a2]"v"(p2), [a3]"v"(p3)
                : "memory");
            __builtin_amdgcn_sched_barrier(0);

            unsigned short* dst = hHi + r0s * WST + 8 * c16;
            *(v4u*)(dst + 0 * 4 * WST) = v0;
            *(v4u*)(dst + 1 * 4 * WST) = v1;
            *(v4u*)(dst + 2 * 4 * WST) = v2;
            *(v4u*)(dst + 3 * 4 * WST) = v3;
            __syncthreads();   // stage complete before h-GEMM reads

            const unsigned short* aHh = hHi + rA * WST + 8 * g;
            #pragma unroll
            for (int kt = 0; kt < 16; kt += 2) {
                v8s ah0 = *(const v8s*)(aHh + kt * 32);
                v8s ah1 = *(const v8s*)(aHh + (kt + 1) * 32);
                v8s bh0 = *(const v8s*)(bHh + kt * 32);
                v8s bh1 = *(const v8s*)(bHh + (kt + 1) * 32);
                acc0 = MFMA(ah0, bh0, acc0);
                acc1 = MFMA(ah1, bh1, acc1);
            }
        }
        acc0 = acc0 + acc1;
        if (L0) acc0 += (acc4 + acc5);

        // ---- in-wave 4x4 gate transpose ----
        float pi_, pf_, pg_, po_;
        {
            const float x0 = acc0[0], x1 = acc0[1], x2 = acc0[2], x3 = acc0[3];
            const float n0 = __shfl_xor(x0, 1), n1 = __shfl_xor(x1, 1);
            const float n2 = __shfl_xor(x2, 1), n3 = __shfl_xor(x3, 1);
            const float a0 = (p & 1) ? n1 : x0;
            const float a1 = (p & 1) ? x1 : n0;
            const float a2 = (p & 1) ? n3 : x2;
            const float a3 = (p & 1) ? x3 : n2;
            const float m0 = __shfl_xor(a0, 2), m1 = __shfl_xor(a1, 2);
            const float m2 = __shfl_xor(a2, 2), m3 = __shfl_xor(a3, 2);
            pi_ = (p & 2) ? m2 : a0;
            pf_ = (p & 2) ? m3 : a1;
            pg_ = (p & 2) ? a2 : m0;
            po_ = (p & 2) ? a3 : m1;
        }

        // ---- gates + state update + publish ----
        {
            const float ig = 1.f / (1.f + __expf(-(pi_ + bi_)));
            const float fg = 1.f / (1.f + __expf(-(pf_ + bf_)));
            const float gg = tanhf(pg_ + bg_);
            const float og = 1.f / (1.f + __expf(-(po_ + bo_)));
            creg = fg * creg + ig * gg;
            const float h = og * tanhf(creg);
            const float hq1 = __shfl_xor(h, 4);
            const float hq2 = __shfl_xor(h, 8);
            const float hq3 = __shfl_xor(hq1, 8);

            // 1) h packet: ONE u64 (4 bf16-hi) per (batch, j-quad)
            if ((jl & 3) == 0) {
                const u64t pk = (u64t)f2b(h)
                              | ((u64t)f2b(hq1) << 16)
                              | ((u64t)f2b(hq2) << 32)
                              | ((u64t)f2b(hq3) << 48);
                u64t* hw = hrbase + (st & 1) * (16 * 128)
                         + (size_t)batch * 128 + ((jbase + jl) >> 2);
                __hip_atomic_store(hw, pk, __ATOMIC_RELAXED, __HIP_MEMORY_SCOPE_AGENT);
            }
            // 2) drain, 3) barrier, 4) flag
            asm volatile("s_waitcnt vmcnt(0)" ::: "memory");
            __syncthreads();
            if (tid == 0)
                __hip_atomic_store(fbase + (size_t)st * 64 + jb, 1u,
                                   __ATOMIC_RELAXED, __HIP_MEMORY_SCOPE_AGENT);

            // 5) y output after the flag
            if (L0) {
                if ((jl & 1) == 0) {
                    const unsigned int pko = (unsigned int)f2b(h)
                                           | ((unsigned int)f2b(hq1) << 16);
                    *((unsigned int*)yout_ + (size_t)gbatch * SS * HH + (size_t)t * HH
                                           + dir * (HH / 2) + ((jbase + jl) >> 1)) = pko;
                }
            } else {
                ((float*)yout_)[((size_t)gbatch * SS + t) * (2 * HH) + dir * HH + jbase + jl] = h;
                if (st == SS - 1) {
                    hn[(dir * BB + gbatch) * HH + jbase + jl] = h;
                    cn[(dir * BB + gbatch) * HH + jbase + jl] = creg;
                }
            }
        }
    }
}

extern "C" void kernel_launch(void* const* d_in, const int* in_sizes, int n_in,
                              void* d_out, int out_size, void* d_ws, size_t ws_size,
                              hipStream_t stream) {
    (void)in_sizes; (void)n_in;

    const float* x      = (const float*)d_in[0];
    const float* Wih_f0 = (const float*)d_in[1];
    const float* Whh_f0 = (const float*)d_in[2];
    const float* b_f0   = (const float*)d_in[3];
    const float* Wih_b0 = (const float*)d_in[4];
    const float* Whh_b0 = (const float*)d_in[5];
    const float* b_b0   = (const float*)d_in[6];
    const float* Wih_f1 = (const float*)d_in[7];
    const float* Whh_f1 = (const float*)d_in[8];
    const float* b_f1   = (const float*)d_in[9];
    const float* Wih_b1 = (const float*)d_in[10];
    const float* Whh_b1 = (const float*)d_in[11];
    const float* b_b1   = (const float*)d_in[12];

    char* ws = (char*)d_ws;
    const size_t Y0B  = (size_t)BB * SS * 2 * HH * 2;           // 33,554,432
    const size_t FLG  = (size_t)2 * 2 * SS * 64 * 4;            // 524,288 / layer
    const size_t HREC = (size_t)2 * 2 * 2 * 16 * 128 * 8;       // 131,072
    const size_t WSP  = (size_t)2 * 2048 * 512 * 2;             // 4,194,304
    const size_t NEED = Y0B + 2 * FLG + HREC + WSP;             // 38,928,384
    if (ws_size < NEED) return;
    if ((size_t)out_size < (size_t)BB * SS * 2 * HH + 4 * BB * HH) return;

    unsigned short* y0     = (unsigned short*)(ws);
    unsigned int*   flags0 = (unsigned int*)(ws + Y0B);
    unsigned int*   flags1 = (unsigned int*)(ws + Y0B + FLG);
    u64t*           hrec   = (u64t*)(ws + Y0B + 2 * FLG);        // shared (sequential)
    unsigned short* wsp    = (unsigned short*)(ws + Y0B + 2 * FLG + HREC);

    float* out = (float*)d_out;                          // [B,S,2H] f32
    float* hn  = out + (size_t)BB * SS * 2 * HH;         // [2,B,H]
    float* cn  = hn + 2 * BB * HH;                       // [2,B,H]

    hipMemsetAsync(ws + Y0B, 0, 2 * FLG, stream);        // zero flags each call

    wih1_presplit<<<1024, 256, 0, stream>>>(Wih_f1, Wih_b1, wsp);

    // LDS: Whh (66,560) + Wih-half (66,560) + hHi (16,640) = 149,760
    constexpr int SMB = WR * WST * 2 + WR * WST * 2 + 16 * WST * 2;
    hipFuncSetAttribute(reinterpret_cast<const void*>(lstm_layer<512,  true>),
                        hipFuncAttributeMaxDynamicSharedMemorySize, SMB);
    hipFuncSetAttribute(reinterpret_cast<const void*>(lstm_layer<1024, false>),
                        hipFuncAttributeMaxDynamicSharedMemorySize, SMB);

    lstm_layer<512, true><<<128, 256, SMB, stream>>>(
        x, Wih_f0, Whh_f0, b_f0, Wih_b0, Whh_b0, b_b0,
        nullptr, (void*)y0, hrec, flags0, nullptr, nullptr);

    lstm_layer<1024, false><<<128, 256, SMB, stream>>>(
        y0, Wih_f1, Whh_f1, b_f1, Wih_b1, Whh_b1, b_b1,
        wsp, (void*)out, hrec, flags1, hn, cn);
}

// Round 21
// 6173.091 us; speedup vs baseline: 1.1009x; 1.1009x over previous
//
#include <hip/hip_runtime.h>
#include <cstdint>
#include <cstddef>

#define BB 32
#define SS 512
#define HH 512
#define NBD 64      // blocks per direction
#define JPB 8       // j columns per block
#define WR 32       // W rows per block (4 gates * JPB)
#define WST 520     // Whh/h LDS row stride (bf16 elems; 1040B = 16B row stagger)

typedef short v8s __attribute__((ext_vector_type(8)));
typedef float v4f __attribute__((ext_vector_type(4)));
typedef unsigned int v4u __attribute__((ext_vector_type(4)));
typedef unsigned long long u64t;

static __device__ __forceinline__ float b2f(unsigned short u) {
    union { unsigned int i; float f; } v; v.i = ((unsigned int)u) << 16; return v.f;
}
static __device__ __forceinline__ unsigned short f2b(float f) {
    union { float f; unsigned int i; } v; v.f = f;
    unsigned int u = v.i;
    return (unsigned short)((u + 0x7fffu + ((u >> 16) & 1u)) >> 16);  // RNE
}
static __device__ __forceinline__ void split1(float f, short& hi, short& lo) {
    const unsigned short h = f2b(f);
    hi = (short)h;
    lo = (short)f2b(f - b2f(h));   // exact residual, then RNE
}

#define MFMA(a, b, c) __builtin_amdgcn_mfma_f32_16x16x32_bf16((a), (b), (c), 0, 0, 0)

// One bidirectional layer; persistent blocks, per-timestep producer flags.
// FINAL (r21 = r16 verbatim, the session's best: 6,154 us).
// Architecture: 64 j-blocks/direction; LDS-resident bf16-hi weights (Whh +
// Wih, fragment-ordered rows); h-exchange via bf16-hi x4 u64 packets in a
// parity double-buffer at the coherent point; per-producer flags; fused
// per-thread poll + 16B sc1 batched stage into LDS; in-wave 4x4 gate
// transpose; x-part overlapped with peers' publish latency.
// Per-step cost ~6.7us = cross-XCD rendezvous chain (publish drain -> flag
// propagation -> detect -> data round trip), shown latency-bound by r16-r20:
// byte-halving, transaction-halving, L2-caching, rendezvous-software, batch
// partitioning, and compute overlap all null or negative.
template<int DIN, bool L0>
__global__ __launch_bounds__(256, 1)
void lstm_layer(const void*  __restrict__ xin_,
                const float* __restrict__ Wih_f,  // [4H, DIN] f32
                const float* __restrict__ Whh_f,  // [4H, H]  f32
                const float* __restrict__ b_f,    // [4H]     f32
                const float* __restrict__ Wih_b,
                const float* __restrict__ Whh_b,
                const float* __restrict__ b_b,
                void*  __restrict__ yout_,         // L0: bf16 [B,S,2H]; L1: f32 [B,S,2H]
                u64t*  __restrict__ hrec,          // [2dir][2par][B][H/4] bf16-hi x4
                unsigned int* __restrict__ flags,  // [2dir][S][64], zeroed each call
                float* __restrict__ hn,            // [2][B][H] f32 (L1) or nullptr
                float* __restrict__ cn)            // [2][B][H] f32 (L1) or nullptr
{
    constexpr int NKX = DIN / 32;
    constexpr int NKH = HH / 32;
    constexpr int XST = DIN + 8;     // Wih LDS row stride (16B row stagger)

    extern __shared__ char smem[];
    unsigned short* WhhHi = (unsigned short*)smem;          // [32][WST] reordered rows
    unsigned short* WihHi = WhhHi + WR * WST;               // [32][XST] reordered rows
    unsigned short* hHi   = WihHi + WR * XST;               // [32][WST] batch-major

    const int tid   = threadIdx.x;
    const int dir   = blockIdx.x >> 6;
    const int jb    = blockIdx.x & 63;
    const int jbase = jb * JPB;

    const float* Wih = dir ? Wih_b : Wih_f;
    const float* Whh = dir ? Whh_b : Whh_f;
    const float* bv  = dir ? b_b  : b_f;

    // ---- stage Whh-hi and Wih-hi into LDS (reordered: LDS row r = output col;
    //      W row R = (r&3)*HH + jbase + (r>>2)) ----
    {
        const int r = tid >> 3;
        const int R = (r & 3) * HH + jbase + (r >> 2);
        {
            const int c0 = (tid & 7) * 64;
            const float* src = Whh + (size_t)R * HH + c0;
            #pragma unroll
            for (int c = 0; c < 64; c += 8) {
                v8s hi;
                #pragma unroll
                for (int e = 0; e < 8; ++e) hi[e] = (short)f2b(src[c + e]);
                *(v8s*)(WhhHi + r * WST + c0 + c) = hi;
            }
        }
        {
            const int c0 = (tid & 7) * (DIN / 8);
            const float* src = Wih + (size_t)R * DIN + c0;
            #pragma unroll
            for (int c = 0; c < DIN / 8; c += 8) {
                v8s hi;
                #pragma unroll
                for (int e = 0; e < 8; ++e) hi[e] = (short)f2b(src[c + e]);
                *(v8s*)(WihHi + r * XST + c0 + c) = hi;
            }
        }
    }

    const int lane = tid & 63;
    const int wv   = tid >> 6;
    const int mi   = wv & 1;         // M-frag (batch half)
    const int ni   = wv >> 1;        // N-frag (gate-col half)
    const int g    = lane >> 4;      // k-group
    const int rA   = lane & 15;

    const int brow = mi * 16 + rA;   // batch row (A-frag)
    const int col  = ni * 16 + rA;   // this lane's output column c (= LDS B row)
    const int jl   = col >> 2;       // j within block (0..7)
    const int p    = rA & 3;         // lane pos in 4-lane gate subgroup

    // per-lane biases for j = jbase + jl (all 4 gates)
    const float bi_ = bv[0 * HH + jbase + jl];
    const float bf_ = bv[1 * HH + jbase + jl];
    const float bg_ = bv[2 * HH + jbase + jl];
    const float bo_ = bv[3 * HH + jbase + jl];

    __syncthreads();

    const float*          aXf = L0 ? (const float*)xin_ + (size_t)brow * SS * DIN + 8 * g : nullptr;
    const unsigned short* aXb = L0 ? nullptr : (const unsigned short*)xin_ + (size_t)brow * SS * DIN + 8 * g;
    const unsigned short* bHh = WhhHi + col * WST + 8 * g;   // h-part B (LDS)
    const unsigned short* bHx = WihHi + col * XST + 8 * g;   // x-part B (LDS)

    unsigned int* fbase = flags + (size_t)dir * SS * 64;     // per-direction flag plane

    const int batch = mi * 16 + 4 * g + p;   // this lane's epilogue batch
    const int pq = tid & 63;                 // pair-quad: cols 8pq..8pq+7 (one producer)
    const int r0 = tid >> 6;                 // base row 0..3
    float creg = 0.f;

    for (int st = 0; st < SS; ++st) {
        const int t = dir ? (SS - 1 - st) : st;

        v4f acc0 = {0,0,0,0}, acc1 = {0,0,0,0};
        v4f acc4 = {0,0,0,0}, acc5 = {0,0,0,0};   // L0 a-lo terms

        // ---- x-part (pre-poll; runs under peers' publish latency) ----
        if (L0) {
            const float* aX = aXf + (size_t)t * DIN;
            #pragma unroll
            for (int kt = 0; kt < NKX; kt += 2) {
                v8s ah0, al0, ah1, al1;
                #pragma unroll
                for (int e = 0; e < 8; ++e) {
                    short h, l;
                    split1(aX[kt * 32 + e], h, l);       ah0[e] = h; al0[e] = l;
                    split1(aX[(kt + 1) * 32 + e], h, l); ah1[e] = h; al1[e] = l;
                }
                v8s wh0 = *(const v8s*)(bHx + kt * 32);
                v8s wh1 = *(const v8s*)(bHx + (kt + 1) * 32);
                acc0 = MFMA(ah0, wh0, acc0);
                acc1 = MFMA(ah1, wh1, acc1);
                acc4 = MFMA(al0, wh0, acc4);
                acc5 = MFMA(al1, wh1, acc5);
            }
        } else {
            const unsigned short* aX = aXb + (size_t)t * DIN;
            #pragma unroll
            for (int kt = 0; kt < NKX; kt += 2) {
                v8s a0 = *(const v8s*)(aX + kt * 32);
                v8s a1 = *(const v8s*)(aX + (kt + 1) * 32);
                v8s wh0 = *(const v8s*)(bHx + kt * 32);
                v8s wh1 = *(const v8s*)(bHx + (kt + 1) * 32);
                acc0 = MFMA(a0, wh0, acc0);
                acc1 = MFMA(a1, wh1, acc1);
            }
        }

        // ---- fused poll+stage (16B sc1 loads; one asm block, single waitcnt) ----
        if (st > 0) {
            {
                const unsigned int* f = fbase + (size_t)(st - 1) * 64 + pq;
                int guard = 0;
                while (!__hip_atomic_load(f, __ATOMIC_RELAXED,
                                          __HIP_MEMORY_SCOPE_AGENT)) {
                    __builtin_amdgcn_s_sleep(1);
                    if (++guard > (1 << 26)) break;   // anti-hang escape
                }
            }
            const char* hb = (const char*)(hrec
                + (size_t)(dir * 2 + ((st - 1) & 1)) * (BB * HH / 4))
                + (size_t)r0 * 1024 + (size_t)pq * 16;
            const char* p0 = hb;
            const char* p1 = hb + 1 * 4096;
            const char* p2 = hb + 2 * 4096;
            const char* p3 = hb + 3 * 4096;
            const char* p4 = hb + 4 * 4096;
            const char* p5 = hb + 5 * 4096;
            const char* p6 = hb + 6 * 4096;
            const char* p7 = hb + 7 * 4096;
            v4u v0, v1, v2, v3, v4, v5, v6, v7;
            asm volatile(
                "global_load_dwordx4 %[o0], %[a0], off sc1\n\t"
                "global_load_dwordx4 %[o1], %[a1], off sc1\n\t"
                "global_load_dwordx4 %[o2], %[a2], off sc1\n\t"
                "global_load_dwordx4 %[o3], %[a3], off sc1\n\t"
                "global_load_dwordx4 %[o4], %[a4], off sc1\n\t"
                "global_load_dwordx4 %[o5], %[a5], off sc1\n\t"
                "global_load_dwordx4 %[o6], %[a6], off sc1\n\t"
                "global_load_dwordx4 %[o7], %[a7], off sc1\n\t"
                "s_waitcnt vmcnt(0)"
                : [o0]"=&v"(v0), [o1]"=&v"(v1), [o2]"=&v"(v2), [o3]"=&v"(v3),
                  [o4]"=&v"(v4), [o5]"=&v"(v5), [o6]"=&v"(v6), [o7]"=&v"(v7)
                : [a0]"v"(p0), [a1]"v"(p1), [a2]"v"(p2), [a3]"v"(p3),
                  [a4]"v"(p4), [a5]"v"(p5), [a6]"v"(p6), [a7]"v"(p7)
                : "memory");
            __builtin_amdgcn_sched_barrier(0);

            unsigned short* dst = hHi + r0 * WST + 8 * pq;   // +4 rows = +4*WST
            *(v4u*)(dst + 0 * 4 * WST) = v0;
            *(v4u*)(dst + 1 * 4 * WST) = v1;
            *(v4u*)(dst + 2 * 4 * WST) = v2;
            *(v4u*)(dst + 3 * 4 * WST) = v3;
            *(v4u*)(dst + 4 * 4 * WST) = v4;
            *(v4u*)(dst + 5 * 4 * WST) = v5;
            *(v4u*)(dst + 6 * 4 * WST) = v6;
            *(v4u*)(dst + 7 * 4 * WST) = v7;
            __syncthreads();

            const unsigned short* aHh = hHi + brow * WST + 8 * g;
            #pragma unroll
            for (int kt = 0; kt < NKH; kt += 2) {
                v8s ah0 = *(const v8s*)(aHh + kt * 32);
                v8s ah1 = *(const v8s*)(aHh + (kt + 1) * 32);
                v8s bh0 = *(const v8s*)(bHh + kt * 32);
                v8s bh1 = *(const v8s*)(bHh + (kt + 1) * 32);
                acc0 = MFMA(ah0, bh0, acc0);
                acc1 = MFMA(ah1, bh1, acc1);
            }
        }
        acc0 = acc0 + acc1;
        if (L0) acc0 += (acc4 + acc5);

        // ---- in-wave 4x4 gate transpose (xor-1, xor-2 butterflies) ----
        float pi_, pf_, pg_, po_;
        {
            const float x0 = acc0[0], x1 = acc0[1], x2 = acc0[2], x3 = acc0[3];
            const float n0 = __shfl_xor(x0, 1), n1 = __shfl_xor(x1, 1);
            const float n2 = __shfl_xor(x2, 1), n3 = __shfl_xor(x3, 1);
            const float a0 = (p & 1) ? n1 : x0;
            const float a1 = (p & 1) ? x1 : n0;
            const float a2 = (p & 1) ? n3 : x2;
            const float a3 = (p & 1) ? x3 : n2;
            const float m0 = __shfl_xor(a0, 2), m1 = __shfl_xor(a1, 2);
            const float m2 = __shfl_xor(a2, 2), m3 = __shfl_xor(a3, 2);
            pi_ = (p & 2) ? m2 : a0;
            pf_ = (p & 2) ? m3 : a1;
            pg_ = (p & 2) ? a2 : m0;
            po_ = (p & 2) ? a3 : m1;
        }

        // ---- gates (torch order i,f,g,o) + state update + publish ----
        {
            const float ig = 1.f / (1.f + __expf(-(pi_ + bi_)));
            const float fg = 1.f / (1.f + __expf(-(pf_ + bf_)));
            const float gg = tanhf(pg_ + bg_);
            const float og = 1.f / (1.f + __expf(-(po_ + bo_)));
            creg = fg * creg + ig * gg;
            const float h = og * tanhf(creg);
            const float hq1 = __shfl_xor(h, 4);
            const float hq2 = __shfl_xor(h, 8);
            const float hq3 = __shfl_xor(hq1, 8);

            // 1) h-exchange: ONE u64 (4 bf16-hi) per (batch, j-quad)
            if ((jl & 3) == 0) {
                const u64t pk = (u64t)f2b(h)
                              | ((u64t)f2b(hq1) << 16)
                              | ((u64t)f2b(hq2) << 32)
                              | ((u64t)f2b(hq3) << 48);
                u64t* hw = hrec + (size_t)(dir * 2 + (st & 1)) * (BB * HH / 4)
                         + (size_t)batch * (HH / 4) + ((jbase + jl) >> 2);
                __hip_atomic_store(hw, pk, __ATOMIC_RELAXED, __HIP_MEMORY_SCOPE_AGENT);
            }
            // 2) drain vmem, 3) block barrier, 4) flag
            asm volatile("s_waitcnt vmcnt(0)" ::: "memory");
            __syncthreads();
            if (tid == 0)
                __hip_atomic_store(fbase + (size_t)st * 64 + jb, 1u,
                                   __ATOMIC_RELAXED, __HIP_MEMORY_SCOPE_AGENT);

            // 5) y output stores AFTER the flag (drain under next step's x-part)
            if (L0) {
                if ((jl & 1) == 0) {
                    const unsigned int pko = (unsigned int)f2b(h)
                                           | ((unsigned int)f2b(hq1) << 16);
                    *((unsigned int*)yout_ + (size_t)batch * SS * HH + (size_t)t * HH
                                           + dir * (HH / 2) + ((jbase + jl) >> 1)) = pko;
                }
            } else {
                ((float*)yout_)[((size_t)batch * SS + t) * (2 * HH) + dir * HH + jbase + jl] = h;
                if (st == SS - 1) {
                    hn[(dir * BB + batch) * HH + jbase + jl] = h;
                    cn[(dir * BB + batch) * HH + jbase + jl] = creg;
                }
            }
        }
    }
}

extern "C" void kernel_launch(void* const* d_in, const int* in_sizes, int n_in,
                              void* d_out, int out_size, void* d_ws, size_t ws_size,
                              hipStream_t stream) {
    (void)in_sizes; (void)n_in;

    const float* x      = (const float*)d_in[0];
    const float* Wih_f0 = (const float*)d_in[1];
    const float* Whh_f0 = (const float*)d_in[2];
    const float* b_f0   = (const float*)d_in[3];
    const float* Wih_b0 = (const float*)d_in[4];
    const float* Whh_b0 = (const float*)d_in[5];
    const float* b_b0   = (const float*)d_in[6];
    const float* Wih_f1 = (const float*)d_in[7];
    const float* Whh_f1 = (const float*)d_in[8];
    const float* b_f1   = (const float*)d_in[9];
    const float* Wih_b1 = (const float*)d_in[10];
    const float* Whh_b1 = (const float*)d_in[11];
    const float* b_b1   = (const float*)d_in[12];

    // ws: [0,32Mi) y0 bf16; +256K flags0[2][512][64]; +256K flags1; +128K hrec
    char* ws = (char*)d_ws;
    const size_t Y0B  = (size_t)BB * SS * 2 * HH * 2;             // 33,554,432
    const size_t FLG  = (size_t)2 * SS * 64 * 4;                  // 262,144 each
    const size_t HREC = (size_t)2 * 2 * BB * (HH / 4) * 8;        // 131,072
    const size_t NEED = Y0B + 2 * FLG + HREC;                     // 34,209,792
    if (ws_size < NEED) return;
    if ((size_t)out_size < (size_t)BB * SS * 2 * HH + 4 * BB * HH) return;

    unsigned short* y0     = (unsigned short*)(ws);
    unsigned int*   flags0 = (unsigned int*)(ws + Y0B);
    unsigned int*   flags1 = (unsigned int*)(ws + Y0B + FLG);
    u64t*           hrec   = (u64t*)(ws + Y0B + 2 * FLG);         // shared (sequential)

    float* out = (float*)d_out;                          // [B,S,2H] f32
    float* hn  = out + (size_t)BB * SS * 2 * HH;         // [2,B,H]
    float* cn  = hn + 2 * BB * HH;                       // [2,B,H]

    hipMemsetAsync(ws + Y0B, 0, 2 * FLG, stream);        // zero flags each call

    // LDS: WhhHi (33,280) + WihHi (L0: 33,280 / L1: 66,048) + hHi (33,280)
    constexpr int SMB0 = WR * WST * 2 + WR * (512 + 8) * 2 + BB * WST * 2;    //  99,840
    constexpr int SMB1 = WR * WST * 2 + WR * (1024 + 8) * 2 + BB * WST * 2;   // 132,608
    hipFuncSetAttribute(reinterpret_cast<const void*>(lstm_layer<512,  true>),
                        hipFuncAttributeMaxDynamicSharedMemorySize, SMB0);
    hipFuncSetAttribute(reinterpret_cast<const void*>(lstm_layer<1024, false>),
                        hipFuncAttributeMaxDynamicSharedMemorySize, SMB1);

    lstm_layer<512, true><<<128, 256, SMB0, stream>>>(
        x, Wih_f0, Whh_f0, b_f0, Wih_b0, Whh_b0, b_b0,
        (void*)y0, hrec, flags0, nullptr, nullptr);

    lstm_layer<1024, false><<<128, 256, SMB1, stream>>>(
        y0, Wih_f1, Whh_f1, b_f1, Wih_b1, Whh_b1, b_b1,
        (void*)out, hrec, flags1, hn, cn);
}